// Round 8
// baseline (186.891 us; speedup 1.0000x reference)
//
#include <hip/hip_runtime.h>
#include <hip/hip_bf16.h>
#include <cstdint>
#include <cstddef>

#define N_NODES 50000
#define N_EDGES 800000
#define IN_DIM 256
#define HC 128          // HEADS*OUT_DIM
#define HEADS 4
#define NEG_SLOPE 0.2f
#define LN_EPS 1e-5f

#define NGB ((N_NODES + 63) / 64)     // 782 GEMM blocks (also 782 pass-A blocks)
#define CAP 64                        // rec slots per node; deg~Poisson(16),
                                      // P(any deg>=64) ~ 1e-14, fixed seed
#define NBUCK 196                     // dst>>8 buckets (50000/256 -> 0..195)
#define CAP_PB 32                     // arena slots per (block,bucket);
                                      // Poisson(5.2): P(>=32) ~ 1e-16/cell,
                                      // ~1e-11 over all 153K cells

typedef _Float16 f16x8 __attribute__((ext_vector_type(8)));
typedef _Float16 f16x2 __attribute__((ext_vector_type(2)));
typedef float f32x4 __attribute__((ext_vector_type(4)));

__device__ __forceinline__ float lrelu(float x) { return x > 0.f ? x : NEG_SLOPE * x; }
__device__ __forceinline__ unsigned pack_h2(float a, float b) {
    f16x2 h; h[0] = (_Float16)a; h[1] = (_Float16)b;
    return *(unsigned*)&h;
}

// ---------------------------------------------------------------------------
// D1 (fused): interleaved block roles, NO inter-role dependency, and
// ZERO GLOBAL ATOMICS anywhere in the pipeline.
//   odd blocks  -> CSR pass A: rank 1024 edges into 196 dst-buckets via LDS
//                  atomics, write each edge to a BLOCK-PRIVATE 32-slot arena
//                  segment (static base = (bk*782+blk)*32 — no runtime
//                  reservation). Round-6 lesson: the per-bucket global
//                  atomicAdd hit the same 196 addresses from 782 blocks
//                  (153K RMWs on 13 cachelines) and stalled the kernel.
//                  Per-block bucket counts -> plain cnt_tab (no poison use).
//   even blocks -> h = x@W MFMA GEMM (round-1 body, measured best).
// Fragment layout: chunk c = ((kt*8+nt)*64 + quad*16 + col),
// element j = W[(kt*32+quad*8+j)*HC + nt*16+col].
// ---------------------------------------------------------------------------
__global__ __launch_bounds__(256) void k_fused(
    const float* __restrict__ x, const float* __restrict__ W,
    const int* __restrict__ ei,
    const float* __restrict__ att_src, const float* __restrict__ att_dst,
    _Float16* __restrict__ h16, float* __restrict__ a_s, float* __restrict__ a_d,
    int* __restrict__ cnt_tab, int2* __restrict__ arena)
{
    __shared__ _Float16 Wlds[32768];   // 64 KB; pass-A blocks reuse head as cnt
    const int tid = threadIdx.x;
    const int b = blockIdx.x;

    if (b & 1) {
        // ---- CSR pass A: LDS rank + static block-private arena segments
        int* cnt = (int*)Wlds;           // [256], 196 used
        const int blk = b >> 1;
        const int eb = blk << 10;
        cnt[tid] = 0;
        __syncthreads();
        int src[4], dst[4], rk[4], bk[4];
        bool valid[4];
#pragma unroll
        for (int it = 0; it < 4; ++it) {
            int e = eb + it * 256 + tid;
            valid[it] = (e < N_EDGES);
            src[it] = 0; dst[it] = 0; bk[it] = 0; rk[it] = 0;
            if (valid[it]) {
                src[it] = ei[e];
                dst[it] = ei[N_EDGES + e];
                bk[it]  = dst[it] >> 8;
                rk[it]  = atomicAdd(&cnt[bk[it]], 1);     // LDS: cheap
            }
        }
#pragma unroll
        for (int it = 0; it < 4; ++it) {
            if (valid[it]) {
                int p = ((bk[it] * NGB + blk) << 5) + rk[it];   // static base
                arena[p] = (int2){src[it], dst[it]};
            }
        }
        __syncthreads();
        if (tid < NBUCK) cnt_tab[blk * NBUCK + tid] = cnt[tid];
        return;
    }

    // ---- GEMM role ----
    const int gb   = b >> 1;
    const int wave = tid >> 6;
    const int lane = tid & 63;
    const int col  = lane & 15;
    const int quad = lane >> 4;
    const int m0   = gb * 64 + wave * 16;

    const int rowA = min(m0 + col, N_NODES - 1);       // clamp tail; stores guarded
    const float* xrow = x + (size_t)rowA * IN_DIM + quad * 8;

    // full-row preload: 16 independent dwordx4 in flight (hide HBM latency)
    float4 xr[16];
#pragma unroll
    for (int kt = 0; kt < 8; ++kt) {
        xr[2 * kt]     = *(const float4*)(xrow + kt * 32);
        xr[2 * kt + 1] = *(const float4*)(xrow + kt * 32 + 4);
    }

    // stage W -> Wlds, converting f32->f16 in fragment order (single stage)
    {
#pragma unroll
        for (int it = 0; it < 16; ++it) {
            int c = it * 256 + tid;            // 0..4095
            int ccol = c & 15, cquad = (c >> 4) & 3, cnt_ = (c >> 6) & 7, ckt = c >> 9;
            const float* wp = W + (size_t)(ckt * 32 + cquad * 8) * HC + cnt_ * 16 + ccol;
            f16x8 v;
#pragma unroll
            for (int j = 0; j < 8; ++j) v[j] = (_Float16)wp[j * HC];
            *(f16x8*)(Wlds + (size_t)c * 8) = v;
        }
    }
    __syncthreads();

    f32x4 acc[8];
#pragma unroll
    for (int nt = 0; nt < 8; ++nt) acc[nt] = (f32x4){0.f, 0.f, 0.f, 0.f};

#pragma unroll
    for (int kt = 0; kt < 8; ++kt) {
        float4 xa = xr[2 * kt], xb = xr[2 * kt + 1];
        f16x8 a;
        a[0] = (_Float16)xa.x; a[1] = (_Float16)xa.y;
        a[2] = (_Float16)xa.z; a[3] = (_Float16)xa.w;
        a[4] = (_Float16)xb.x; a[5] = (_Float16)xb.y;
        a[6] = (_Float16)xb.z; a[7] = (_Float16)xb.w;
#pragma unroll
        for (int nt = 0; nt < 8; ++nt) {
            f16x8 bb = *(const f16x8*)&Wlds[((kt * 8 + nt) * 64 + quad * 16 + col) * 8];
            acc[nt] = __builtin_amdgcn_mfma_f32_16x16x32_f16(a, bb, acc[nt], 0, 0, 0);
        }
    }

    // ---- epilogue: paired h2 stores (4B, permuted pair layout) ----
    // pair p = a2*16+col holds channels (32*a2+col, 32*a2+16+col); head(p)=p>>4.
    f16x2* h2g = (f16x2*)h16;
#pragma unroll
    for (int a2 = 0; a2 < 4; ++a2) {
#pragma unroll
        for (int r = 0; r < 4; ++r) {
            int row = m0 + quad * 4 + r;
            if (row < N_NODES) {
                f16x2 hv;
                hv[0] = (_Float16)acc[2 * a2][r];
                hv[1] = (_Float16)acc[2 * a2 + 1][r];
                h2g[(size_t)row * 64 + a2 * 16 + col] = hv;
            }
        }
    }

    // ---- per-(row,head) att dots (head = nt>>1) ----
    float pS[4][4], pD[4][4];
#pragma unroll
    for (int hd = 0; hd < 4; ++hd)
#pragma unroll
        for (int r = 0; r < 4; ++r) { pS[hd][r] = 0.f; pD[hd][r] = 0.f; }

#pragma unroll
    for (int nt = 0; nt < 8; ++nt) {
        int ch = nt * 16 + col;
        float sv = att_src[ch], dv = att_dst[ch];
        int hd = nt >> 1;
#pragma unroll
        for (int r = 0; r < 4; ++r) {
            pS[hd][r] += acc[nt][r] * sv;
            pD[hd][r] += acc[nt][r] * dv;
        }
    }
#pragma unroll
    for (int off = 1; off < 16; off <<= 1) {
#pragma unroll
        for (int hd = 0; hd < 4; ++hd)
#pragma unroll
            for (int r = 0; r < 4; ++r) {
                pS[hd][r] += __shfl_xor(pS[hd][r], off, 16);
                pD[hd][r] += __shfl_xor(pD[hd][r], off, 16);
            }
    }
    if (col == 0) {
#pragma unroll
        for (int r = 0; r < 4; ++r) {
            int row = m0 + quad * 4 + r;
            if (row < N_NODES) {
#pragma unroll
                for (int hd = 0; hd < 4; ++hd) {
                    a_s[row * HEADS + hd] = pS[hd][r];
                    a_d[row * HEADS + hd] = pD[hd][r];
                }
            }
        }
    }
}

// ---------------------------------------------------------------------------
// D2: CSR pass B. One block per bucket at 1024 threads. Thread t<782 walks
// pass-A block t's private segment for this bucket (mean 5.2 edges, cap 32),
// LDS-atomic re-ranks into the fixed-CAP rec rows (contiguous 64KB region
// per block). counts written PLAIN. No global atomics.
// ---------------------------------------------------------------------------
__global__ __launch_bounds__(1024) void k_bucket(
    const int2* __restrict__ arena, const int* __restrict__ cnt_tab,
    int* __restrict__ rec, int* __restrict__ counts)
{
    __shared__ int cnt[256];
    const int b = blockIdx.x, tid = threadIdx.x;
    if (tid < 256) cnt[tid] = 0;
    __syncthreads();
    if (tid < NGB) {
        int m = cnt_tab[tid * NBUCK + b];
        const int2* seg = arena + (((size_t)b * NGB + tid) << 5);
        for (int i = 0; i < m; ++i) {
            int2 ed = seg[i];
            int r = atomicAdd(&cnt[ed.y & 255], 1);   // LDS
            rec[((size_t)ed.y << 6) + r] = ed.x;
        }
    }
    __syncthreads();
    if (tid < 256) {
        int n = (b << 8) + tid;
        if (n < N_NODES) counts[n] = cnt[tid];
    }
}

// ---------------------------------------------------------------------------
// D3: gather, one wave per node. deg = counts[n] (plain); records at n*64.
// Edge weights inline (16B L2-resident a_s gather + 4 expf per record).
// 8-deep inner pipeline — the round-1/3 config (VGPR 28, ~65% occupancy).
// Round-4's 16-deep variant raised VGPR to 48, dropped occupancy to 42%,
// and regressed: this kernel hides latency with wave count, not per-wave ILP.
// Lane = pair p: channels c0=32*(p>>4)+(p&15), c1=c0+16 (k_fused's permuted
// h2 layout); head = p>>4. LayerNorm is permutation-invariant.
// ---------------------------------------------------------------------------
__global__ __launch_bounds__(256) void k_gather(
    const int* __restrict__ counts, const int* __restrict__ rec,
    const float* __restrict__ a_s, const float* __restrict__ a_d,
    const _Float16* __restrict__ h16, const float* __restrict__ bias,
    const float* __restrict__ gamma, const float* __restrict__ beta,
    float* __restrict__ out)
{
    __shared__ int   lsrc[256];   // [wave*64 + j]
    __shared__ uint2 lw[256];     // 4 packed f16 weights per record

    int gid = blockIdx.x * 256 + threadIdx.x;
    int n = gid >> 6, lane = gid & 63;
    if (n >= N_NODES) return;

    const int wbase = (threadIdx.x >> 6) * 64;     // wave-private LDS region
    const int beg = n << 6;
    const int deg = counts[n];
    const int hd = lane >> 4;
    const f16x2* h2 = (const f16x2*)h16;
    const unsigned short* lwh = (const unsigned short*)&lw[wbase];  // [j*4+hd]

    const float4 ad4 = *(const float4*)(a_d + (size_t)n * HEADS);  // broadcast
    const float adh = (hd == 0) ? ad4.x : (hd == 1) ? ad4.y : (hd == 2) ? ad4.z : ad4.w;
    const float wSelf = __expf(lrelu(a_s[n * HEADS + hd] + adh));
    float den = wSelf;
    f16x2 hv = h2[(size_t)n * 64 + lane];
    float acc0 = (float)hv[0] * wSelf;
    float acc1 = (float)hv[1] * wSelf;

    for (int base = 0; base < deg; base += 64) {
        int nc = min(64, deg - base);
        if (lane < nc) {
            int src = rec[beg + base + lane];          // 256B contiguous/node
            lsrc[wbase + lane] = src;
            float4 s4 = *(const float4*)(a_s + (size_t)src * HEADS);  // L2-res
            float w0 = __expf(lrelu(s4.x + ad4.x));
            float w1 = __expf(lrelu(s4.y + ad4.y));
            float w2 = __expf(lrelu(s4.z + ad4.z));
            float w3 = __expf(lrelu(s4.w + ad4.w));
            lw[wbase + lane] = (uint2){pack_h2(w0, w1), pack_h2(w2, w3)};
        }
        // wave-synchronous LDS produce->consume (single wave), no barrier
        int j = 0;
        for (; j + 8 <= nc; j += 8) {
            int s[8]; float w[8]; f16x2 hh[8];
#pragma unroll
            for (int k = 0; k < 8; ++k) {
                s[k] = lsrc[wbase + j + k];                         // broadcast
                unsigned short uw = lwh[(j + k) * 4 + hd];          // 2-addr, free
                _Float16 wf = *(_Float16*)&uw;
                w[k] = (float)wf;
            }
#pragma unroll
            for (int k = 0; k < 8; ++k) hh[k] = h2[(size_t)s[k] * 64 + lane];
#pragma unroll
            for (int k = 0; k < 8; ++k) {
                acc0 += (float)hh[k][0] * w[k];
                acc1 += (float)hh[k][1] * w[k];
                den  += w[k];
            }
        }
        for (; j < nc; ++j) {
            int s0 = lsrc[wbase + j];
            unsigned short uw = lwh[j * 4 + hd];
            _Float16 wf = *(_Float16*)&uw;
            float w0 = (float)wf;
            f16x2 hx = h2[(size_t)s0 * 64 + lane];
            acc0 += (float)hx[0] * w0;
            acc1 += (float)hx[1] * w0;
            den  += w0;
        }
    }

    // ---- epilogue: normalize + bias + LayerNorm + ELU (permuted channels) ----
    const int c0 = (lane >> 4) * 32 + (lane & 15);
    const int c1 = c0 + 16;
    float v0 = acc0 / den + bias[c0];
    float v1 = acc1 / den + bias[c1];
    float s = v0 + v1;
#pragma unroll
    for (int off = 32; off; off >>= 1) s += __shfl_xor(s, off, 64);
    float mu = s * (1.f / 128.f);
    float d0 = v0 - mu, d1 = v1 - mu;
    float q = d0 * d0 + d1 * d1;
#pragma unroll
    for (int off = 32; off; off >>= 1) q += __shfl_xor(q, off, 64);
    float rs = rsqrtf(q * (1.f / 128.f) + LN_EPS);
    float o0 = d0 * rs * gamma[c0] + beta[c0];
    float o1 = d1 * rs * gamma[c1] + beta[c1];
    o0 = o0 > 0.f ? o0 : __expf(o0) - 1.f;
    o1 = o1 > 0.f ? o1 : __expf(o1) - 1.f;
    out[(size_t)n * HC + c0] = o0;
    out[(size_t)n * HC + c1] = o1;
}

extern "C" void kernel_launch(void* const* d_in, const int* in_sizes, int n_in,
                              void* d_out, int out_size, void* d_ws, size_t ws_size,
                              hipStream_t stream) {
    const float* x       = (const float*)d_in[0];
    const int*   ei      = (const int*)d_in[1];   // [2, E] int32: row0=src, row1=dst
    const float* W       = (const float*)d_in[2];
    const float* att_src = (const float*)d_in[3];
    const float* att_dst = (const float*)d_in[4];
    const float* bias    = (const float*)d_in[5];
    const float* gamma   = (const float*)d_in[6];
    const float* beta    = (const float*)d_in[7];
    float* out = (float*)d_out;

    char* ws = (char*)d_ws;
    // layout (8/16B-aligned): h16 12.8MB | a_s .8 | a_d .8 | rec 12.8MB |
    //   counts 200KB | cnt_tab 613KB | arena 39.2MB (196x782x32 int2)
    _Float16* h16     = (_Float16*)(ws);
    float*    a_s     = (float*)(ws + 12800000);
    float*    a_d     = (float*)(ws + 13600000);
    int*      rec     = (int*)  (ws + 14400000);   // 12.8 MB
    int*      counts  = (int*)  (ws + 27200000);   // 200 KB
    int*      cnt_tab = (int*)  (ws + 27400000);   // 613,088 B
    int2*     arena   = (int2*) (ws + 28020000);   // 39,237,632 B

    // D1: fused CSR pass A (odd blocks, atomic-free) + MFMA GEMM (even)
    k_fused<<<2 * NGB, 256, 0, stream>>>(x, W, ei, att_src, att_dst,
                                         h16, a_s, a_d, cnt_tab, arena);
    // D2: CSR pass B — per-bucket segment-walk re-rank, 16 waves/block
    k_bucket<<<NBUCK, 1024, 0, stream>>>(arena, cnt_tab, rec, counts);
    // D3: per-node softmax-aggregate (inline edge weights) + LayerNorm + ELU
    k_gather<<<(N_NODES * 64 + 255) / 256, 256, 0, stream>>>(
        counts, rec, a_s, a_d, h16, bias, gamma, beta, out);
}

// Round 10
// 177.174 us; speedup vs baseline: 1.0548x; 1.0548x over previous
//
#include <hip/hip_runtime.h>
#include <hip/hip_bf16.h>
#include <cstdint>
#include <cstddef>

#define N_NODES 50000
#define N_EDGES 800000
#define IN_DIM 256
#define HC 128          // HEADS*OUT_DIM
#define HEADS 4
#define NEG_SLOPE 0.2f
#define LN_EPS 1e-5f

#define NGB ((N_NODES + 63) / 64)     // 782 GEMM blocks (also 782 pass-A blocks)
#define CAP 64                        // rec slots per node; deg~Poisson(16),
                                      // P(any deg>=64) ~ 1e-14, fixed seed
#define NBUCK 196                     // dst>>8 buckets (50000/256 -> 0..195)
#define CAP_PB 32                     // arena slots per (block,bucket);
                                      // Poisson(5.2): P(>=32) ~ 1e-16/cell

typedef _Float16 f16x8 __attribute__((ext_vector_type(8)));
typedef _Float16 f16x2 __attribute__((ext_vector_type(2)));
typedef float f32x4 __attribute__((ext_vector_type(4)));

__device__ __forceinline__ float lrelu(float x) { return x > 0.f ? x : NEG_SLOPE * x; }
__device__ __forceinline__ unsigned pack_h2(float a, float b) {
    f16x2 h; h[0] = (_Float16)a; h[1] = (_Float16)b;
    return *(unsigned*)&h;
}

// ---------------------------------------------------------------------------
// D1: W16 prep (blocks 0..15) + CSR pass A (blocks 16..797). DE-FUSED from
// the GEMM: rounds 3/6/8 proved the fused kernel's 45us was structural, and
// the 64KB Wlds taxed pass-A blocks (need 1KB) down to 2 blocks/CU. Here
// LDS = 1KB -> high occupancy for the latency-bound edge scatter.
//   prep:  W16 chunk c = ((kt*8+nt)*64 + quad*16 + col), elem j =
//          W[(kt*32+quad*8+j)*HC + nt*16+col]  (round-0 proven formula).
//   passA: LDS-rank 1024 edges into 196 dst-buckets; write to BLOCK-PRIVATE
//          32-slot arena segments (static base, zero global atomics).
// ---------------------------------------------------------------------------
__global__ __launch_bounds__(256) void k_prep_passA(
    const float* __restrict__ W, const int* __restrict__ ei,
    _Float16* __restrict__ W16,
    int* __restrict__ cnt_tab, int2* __restrict__ arena)
{
    __shared__ int cnt[256];
    const int tid = threadIdx.x;
    const int b = blockIdx.x;

    if (b < 16) {
        // ---- W16 prep: fragment-ordered f16 conversion of W (64KB total)
        int c = b * 256 + tid;                 // 0..4095
        int col = c & 15, quad = (c >> 4) & 3, nt = (c >> 6) & 7, kt = c >> 9;
        int n = nt * 16 + col;
        f16x8 v;
#pragma unroll
        for (int j = 0; j < 8; ++j) {
            int k = kt * 32 + quad * 8 + j;
            v[j] = (_Float16)W[k * HC + n];
        }
        *(f16x8*)(W16 + (size_t)c * 8) = v;
        return;
    }

    // ---- CSR pass A ----
    const int blk = b - 16;
    const int eb = blk << 10;
    cnt[tid] = 0;
    __syncthreads();
    int src[4], dst[4], rk[4], bk[4];
    bool valid[4];
#pragma unroll
    for (int it = 0; it < 4; ++it) {
        int e = eb + it * 256 + tid;
        valid[it] = (e < N_EDGES);
        src[it] = 0; dst[it] = 0; bk[it] = 0; rk[it] = 0;
        if (valid[it]) {
            src[it] = ei[e];
            dst[it] = ei[N_EDGES + e];
            bk[it]  = dst[it] >> 8;
            rk[it]  = atomicAdd(&cnt[bk[it]], 1);     // LDS: cheap
        }
    }
#pragma unroll
    for (int it = 0; it < 4; ++it) {
        if (valid[it]) {
            int p = ((bk[it] * NGB + blk) << 5) + rk[it];   // static base
            arena[p] = (int2){src[it], dst[it]};
        }
    }
    __syncthreads();
    if (tid < NBUCK) cnt_tab[blk * NBUCK + tid] = cnt[tid];
}

// ---------------------------------------------------------------------------
// D2: GEMM h = x@W via MFMA, role-pure. W staged from pre-converted W16 by
// a 16-iter uint4 copy (coalesced, L2-resident) — replaces round-8's 128
// strided 4B f32 loads + 128 cvts per thread, which the 124-VGPR budget
// could not pipeline. x preloaded first so 16 dwordx4/lane are in flight
// under the W copy.
// ---------------------------------------------------------------------------
__global__ __launch_bounds__(256) void k_gemm(
    const float* __restrict__ x, const _Float16* __restrict__ W16,
    const float* __restrict__ att_src, const float* __restrict__ att_dst,
    _Float16* __restrict__ h16, float* __restrict__ a_s, float* __restrict__ a_d)
{
    __shared__ _Float16 Wlds[32768];   // 64 KB, fragment-ordered
    const int tid = threadIdx.x;

    const int wave = tid >> 6;
    const int lane = tid & 63;
    const int col  = lane & 15;
    const int quad = lane >> 4;
    const int m0   = blockIdx.x * 64 + wave * 16;

    const int rowA = min(m0 + col, N_NODES - 1);       // clamp tail; stores guarded
    const float* xrow = x + (size_t)rowA * IN_DIM + quad * 8;

    // full-row preload: 16 independent dwordx4 in flight (hide HBM latency)
    float4 xr[16];
#pragma unroll
    for (int kt = 0; kt < 8; ++kt) {
        xr[2 * kt]     = *(const float4*)(xrow + kt * 32);
        xr[2 * kt + 1] = *(const float4*)(xrow + kt * 32 + 4);
    }

    {   // stage: 16 iters x (256 lanes x 16B), lane-contiguous -> conflict-free
        const uint4* g4 = (const uint4*)W16;
        uint4* s4 = (uint4*)Wlds;
#pragma unroll
        for (int it = 0; it < 16; ++it) s4[it * 256 + tid] = g4[it * 256 + tid];
    }
    __syncthreads();

    f32x4 acc[8];
#pragma unroll
    for (int nt = 0; nt < 8; ++nt) acc[nt] = (f32x4){0.f, 0.f, 0.f, 0.f};

#pragma unroll
    for (int kt = 0; kt < 8; ++kt) {
        float4 xa = xr[2 * kt], xb = xr[2 * kt + 1];
        f16x8 a;
        a[0] = (_Float16)xa.x; a[1] = (_Float16)xa.y;
        a[2] = (_Float16)xa.z; a[3] = (_Float16)xa.w;
        a[4] = (_Float16)xb.x; a[5] = (_Float16)xb.y;
        a[6] = (_Float16)xb.z; a[7] = (_Float16)xb.w;
#pragma unroll
        for (int nt = 0; nt < 8; ++nt) {
            f16x8 bb = *(const f16x8*)&Wlds[((kt * 8 + nt) * 64 + quad * 16 + col) * 8];
            acc[nt] = __builtin_amdgcn_mfma_f32_16x16x32_f16(a, bb, acc[nt], 0, 0, 0);
        }
    }

    // ---- epilogue: paired h2 stores (4B, permuted pair layout) ----
    // pair p = a2*16+col holds channels (32*a2+col, 32*a2+16+col); head(p)=p>>4.
    f16x2* h2g = (f16x2*)h16;
#pragma unroll
    for (int a2 = 0; a2 < 4; ++a2) {
#pragma unroll
        for (int r = 0; r < 4; ++r) {
            int row = m0 + quad * 4 + r;
            if (row < N_NODES) {
                f16x2 hv;
                hv[0] = (_Float16)acc[2 * a2][r];
                hv[1] = (_Float16)acc[2 * a2 + 1][r];
                h2g[(size_t)row * 64 + a2 * 16 + col] = hv;
            }
        }
    }

    // ---- per-(row,head) att dots (head = nt>>1) ----
    float pS[4][4], pD[4][4];
#pragma unroll
    for (int hd = 0; hd < 4; ++hd)
#pragma unroll
        for (int r = 0; r < 4; ++r) { pS[hd][r] = 0.f; pD[hd][r] = 0.f; }

#pragma unroll
    for (int nt = 0; nt < 8; ++nt) {
        int ch = nt * 16 + col;
        float sv = att_src[ch], dv = att_dst[ch];
        int hd = nt >> 1;
#pragma unroll
        for (int r = 0; r < 4; ++r) {
            pS[hd][r] += acc[nt][r] * sv;
            pD[hd][r] += acc[nt][r] * dv;
        }
    }
#pragma unroll
    for (int off = 1; off < 16; off <<= 1) {
#pragma unroll
        for (int hd = 0; hd < 4; ++hd)
#pragma unroll
            for (int r = 0; r < 4; ++r) {
                pS[hd][r] += __shfl_xor(pS[hd][r], off, 16);
                pD[hd][r] += __shfl_xor(pD[hd][r], off, 16);
            }
    }
    if (col == 0) {
#pragma unroll
        for (int r = 0; r < 4; ++r) {
            int row = m0 + quad * 4 + r;
            if (row < N_NODES) {
#pragma unroll
                for (int hd = 0; hd < 4; ++hd) {
                    a_s[row * HEADS + hd] = pS[hd][r];
                    a_d[row * HEADS + hd] = pD[hd][r];
                }
            }
        }
    }
}

// ---------------------------------------------------------------------------
// D3: CSR pass B. One block per bucket at 1024 threads. Thread t<782 walks
// pass-A block t's private segment for this bucket (mean 5.2 edges, cap 32),
// LDS-atomic re-ranks into the fixed-CAP rec rows (contiguous 64KB region
// per block). counts written PLAIN. No global atomics.
// ---------------------------------------------------------------------------
__global__ __launch_bounds__(1024) void k_bucket(
    const int2* __restrict__ arena, const int* __restrict__ cnt_tab,
    int* __restrict__ rec, int* __restrict__ counts)
{
    __shared__ int cnt[256];
    const int b = blockIdx.x, tid = threadIdx.x;
    if (tid < 256) cnt[tid] = 0;
    __syncthreads();
    if (tid < NGB) {
        int m = cnt_tab[tid * NBUCK + b];
        const int2* seg = arena + (((size_t)b * NGB + tid) << 5);
        for (int i = 0; i < m; ++i) {
            int2 ed = seg[i];
            int r = atomicAdd(&cnt[ed.y & 255], 1);   // LDS
            rec[((size_t)ed.y << 6) + r] = ed.x;
        }
    }
    __syncthreads();
    if (tid < 256) {
        int n = (b << 8) + tid;
        if (n < N_NODES) counts[n] = cnt[tid];
    }
}

// ---------------------------------------------------------------------------
// D4: gather, one wave per node. deg = counts[n] (plain); records at n*64.
// Edge weights inline (16B L2-resident a_s gather + 4 expf per record).
// 8-deep inner pipeline — VGPR 28, ~65% occupancy (round-4's 16-deep
// variant regressed: this kernel hides latency with wave count, not ILP).
// Lane = pair p: channels c0=32*(p>>4)+(p&15), c1=c0+16 (k_gemm's permuted
// h2 layout); head = p>>4. LayerNorm is permutation-invariant.
// ---------------------------------------------------------------------------
__global__ __launch_bounds__(256) void k_gather(
    const int* __restrict__ counts, const int* __restrict__ rec,
    const float* __restrict__ a_s, const float* __restrict__ a_d,
    const _Float16* __restrict__ h16, const float* __restrict__ bias,
    const float* __restrict__ gamma, const float* __restrict__ beta,
    float* __restrict__ out)
{
    __shared__ int   lsrc[256];   // [wave*64 + j]
    __shared__ uint2 lw[256];     // 4 packed f16 weights per record

    int gid = blockIdx.x * 256 + threadIdx.x;
    int n = gid >> 6, lane = gid & 63;
    if (n >= N_NODES) return;

    const int wbase = (threadIdx.x >> 6) * 64;     // wave-private LDS region
    const int beg = n << 6;
    const int deg = counts[n];
    const int hd = lane >> 4;
    const f16x2* h2 = (const f16x2*)h16;
    const unsigned short* lwh = (const unsigned short*)&lw[wbase];  // [j*4+hd]

    const float4 ad4 = *(const float4*)(a_d + (size_t)n * HEADS);  // broadcast
    const float adh = (hd == 0) ? ad4.x : (hd == 1) ? ad4.y : (hd == 2) ? ad4.z : ad4.w;
    const float wSelf = __expf(lrelu(a_s[n * HEADS + hd] + adh));
    float den = wSelf;
    f16x2 hv = h2[(size_t)n * 64 + lane];
    float acc0 = (float)hv[0] * wSelf;
    float acc1 = (float)hv[1] * wSelf;

    for (int base = 0; base < deg; base += 64) {
        int nc = min(64, deg - base);
        if (lane < nc) {
            int src = rec[beg + base + lane];          // 256B contiguous/node
            lsrc[wbase + lane] = src;
            float4 s4 = *(const float4*)(a_s + (size_t)src * HEADS);  // L2-res
            float w0 = __expf(lrelu(s4.x + ad4.x));
            float w1 = __expf(lrelu(s4.y + ad4.y));
            float w2 = __expf(lrelu(s4.z + ad4.z));
            float w3 = __expf(lrelu(s4.w + ad4.w));
            lw[wbase + lane] = (uint2){pack_h2(w0, w1), pack_h2(w2, w3)};
        }
        // wave-synchronous LDS produce->consume (single wave), no barrier
        int j = 0;
        for (; j + 8 <= nc; j += 8) {
            int s[8]; float w[8]; f16x2 hh[8];
#pragma unroll
            for (int k = 0; k < 8; ++k) {
                s[k] = lsrc[wbase + j + k];                         // broadcast
                unsigned short uw = lwh[(j + k) * 4 + hd];          // 2-addr, free
                _Float16 wf = *(_Float16*)&uw;
                w[k] = (float)wf;
            }
#pragma unroll
            for (int k = 0; k < 8; ++k) hh[k] = h2[(size_t)s[k] * 64 + lane];
#pragma unroll
            for (int k = 0; k < 8; ++k) {
                acc0 += (float)hh[k][0] * w[k];
                acc1 += (float)hh[k][1] * w[k];
                den  += w[k];
            }
        }
        for (; j < nc; ++j) {
            int s0 = lsrc[wbase + j];
            unsigned short uw = lwh[j * 4 + hd];
            _Float16 wf = *(_Float16*)&uw;
            float w0 = (float)wf;
            f16x2 hx = h2[(size_t)s0 * 64 + lane];
            acc0 += (float)hx[0] * w0;
            acc1 += (float)hx[1] * w0;
            den  += w0;
        }
    }

    // ---- epilogue: normalize + bias + LayerNorm + ELU (permuted channels) ----
    const int c0 = (lane >> 4) * 32 + (lane & 15);
    const int c1 = c0 + 16;
    float v0 = acc0 / den + bias[c0];
    float v1 = acc1 / den + bias[c1];
    float s = v0 + v1;
#pragma unroll
    for (int off = 32; off; off >>= 1) s += __shfl_xor(s, off, 64);
    float mu = s * (1.f / 128.f);
    float d0 = v0 - mu, d1 = v1 - mu;
    float q = d0 * d0 + d1 * d1;
#pragma unroll
    for (int off = 32; off; off >>= 1) q += __shfl_xor(q, off, 64);
    float rs = rsqrtf(q * (1.f / 128.f) + LN_EPS);
    float o0 = d0 * rs * gamma[c0] + beta[c0];
    float o1 = d1 * rs * gamma[c1] + beta[c1];
    o0 = o0 > 0.f ? o0 : __expf(o0) - 1.f;
    o1 = o1 > 0.f ? o1 : __expf(o1) - 1.f;
    out[(size_t)n * HC + c0] = o0;
    out[(size_t)n * HC + c1] = o1;
}

extern "C" void kernel_launch(void* const* d_in, const int* in_sizes, int n_in,
                              void* d_out, int out_size, void* d_ws, size_t ws_size,
                              hipStream_t stream) {
    const float* x       = (const float*)d_in[0];
    const int*   ei      = (const int*)d_in[1];   // [2, E] int32: row0=src, row1=dst
    const float* W       = (const float*)d_in[2];
    const float* att_src = (const float*)d_in[3];
    const float* att_dst = (const float*)d_in[4];
    const float* bias    = (const float*)d_in[5];
    const float* gamma   = (const float*)d_in[6];
    const float* beta    = (const float*)d_in[7];
    float* out = (float*)d_out;

    char* ws = (char*)d_ws;
    // layout (8/16B-aligned): h16 12.8MB | a_s .8 | a_d .8 | rec 12.8MB |
    //   counts 200KB | cnt_tab 613KB | arena 39.2MB | W16 64KB
    _Float16* h16     = (_Float16*)(ws);
    float*    a_s     = (float*)(ws + 12800000);
    float*    a_d     = (float*)(ws + 13600000);
    int*      rec     = (int*)  (ws + 14400000);   // 12.8 MB
    int*      counts  = (int*)  (ws + 27200000);   // 200 KB
    int*      cnt_tab = (int*)  (ws + 27400000);   // 613,088 B
    int2*     arena   = (int2*) (ws + 28020000);   // 39,237,632 B
    _Float16* W16     = (_Float16*)(ws + 67260000);// 65,536 B

    // D1: W16 prep (16 blocks) + CSR pass A (782 blocks), 1KB LDS, zero
    //     global atomics
    k_prep_passA<<<16 + NGB, 256, 0, stream>>>(W, ei, W16, cnt_tab, arena);
    // D2: role-pure MFMA GEMM from W16 (uint4-copy staging)
    k_gemm<<<NGB, 256, 0, stream>>>(x, W16, att_src, att_dst, h16, a_s, a_d);
    // D3: CSR pass B — per-bucket segment-walk re-rank, 16 waves/block
    k_bucket<<<NBUCK, 1024, 0, stream>>>(arena, cnt_tab, rec, counts);
    // D4: per-node softmax-aggregate (inline edge weights) + LayerNorm + ELU
    k_gather<<<(N_NODES * 64 + 255) / 256, 256, 0, stream>>>(
        counts, rec, a_s, a_d, h16, bias, gamma, beta, out);
}